// Round 1
// baseline (330.172 us; speedup 1.0000x reference)
//
#include <hip/hip_runtime.h>

namespace {

constexpr int B = 2;
constexpr int N = 200000;
constexpr int C = 16;
constexpr int D = 256;
constexpr int H = 256;
constexpr int W = 32;
constexpr int V = D * H * W;    // 2^21 voxels per batch
constexpr int BV = B * V;       // 4,194,304
constexpr unsigned NIL = 0xFFFFFFFFu;

// Replicate reference op order exactly: (p - lo) / (hi - lo) * dim, trunc, clip.
// (This exact formulation gave absmax 0 in rounds 1-4 — do not change.)
__device__ __forceinline__ int voxel_of(float x, float y, float z) {
    float fx = (x - (-48.0f)) / 96.0f * 256.0f;
    float fy = (y - (-48.0f)) / 96.0f * 256.0f;
    float fz = (z - (-4.0f)) / 5.5f * 32.0f;
    int vx = (int)fx;
    int vy = (int)fy;
    int vz = (int)fz;
    vx = vx < 0 ? 0 : (vx > D - 1 ? D - 1 : vx);
    vy = vy < 0 ? 0 : (vy > H - 1 ? H - 1 : vy);
    vz = vz < 0 ? 0 : (vz > W - 1 ? W - 1 : vz);
    return (vx * H + vy) * W + vz;
}

// NOTE (R4 lesson): no __builtin_nontemporal_* anywhere. NT loads killed the
// L2 hits on head/nxt (290 µs vs 85 µs cached), NT stores amplified WRITE_SIZE.

__global__ __launch_bounds__(256) void init_head(uint4* __restrict__ head4, int n4) {
    int i = blockIdx.x * blockDim.x + threadIdx.x;
    if (i < n4) head4[i] = make_uint4(NIL, NIL, NIL, NIL);
}

// One atomicExch per point: push point idx onto its voxel's intrusive list.
__global__ __launch_bounds__(256) void build_list(
    const float* __restrict__ pts, unsigned* __restrict__ head,
    unsigned* __restrict__ nxt) {
    int idx = blockIdx.x * blockDim.x + threadIdx.x;
    if (idx >= B * N) return;
    const float* p = pts + (size_t)idx * 3;
    int v = voxel_of(p[0], p[1], p[2]);
    int b = idx / N;
    unsigned old = atomicExch(head + (size_t)b * V + v, (unsigned)idx);
    nxt[idx] = old;
}

// One thread per voxel (R5 change). Rationale: the previous 4-voxel-per-thread
// version held s[4][16]+4x gather temps (~130 VGPR -> <=4 waves/SIMD) and
// serialized 4 dependent gather rounds per thread; it was latency-bound, not
// BW-bound. One voxel/thread needs ~<64 VGPR -> 8 waves/SIMD, 4x the waves,
// and exactly one gather round for the dominant (count<=1) case. Empty lanes
// are pure predication (s[] pre-zeroed) — no divergent store paths.
__global__ __launch_bounds__(256) void finalize(
    const unsigned* __restrict__ head, const unsigned* __restrict__ nxt,
    const float4* __restrict__ fts4, float* __restrict__ out) {
    int t = blockIdx.x * blockDim.x + threadIdx.x;
    if (t >= BV) return;
    int b = t >> 21;              // V = 2^21
    int v = t & (V - 1);

    unsigned h = head[t];         // coalesced 256B/wave

    float s[16];
#pragma unroll
    for (int c = 0; c < 16; ++c) s[c] = 0.f;
    float cnt = 0.f;
    unsigned nx = NIL;

    if (h != NIL) {               // ~9.1% of lanes
        const float4* fp = fts4 + (size_t)h * 4;
        float4 f0 = fp[0];
        float4 f1 = fp[1];
        float4 f2 = fp[2];
        float4 f3 = fp[3];        // one 64B line, fully used
        nx = nxt[h];              // L2-resident (nxt = 1.6 MB)
        s[0]  = f0.x; s[1]  = f0.y; s[2]  = f0.z; s[3]  = f0.w;
        s[4]  = f1.x; s[5]  = f1.y; s[6]  = f1.z; s[7]  = f1.w;
        s[8]  = f2.x; s[9]  = f2.y; s[10] = f2.z; s[11] = f2.w;
        s[12] = f3.x; s[13] = f3.y; s[14] = f3.z; s[15] = f3.w;
        cnt = 1.f;
    }

    // Rare tail: voxels with >= 2 points (~4.4% of occupied voxels).
    // Plain divergent loop; lanes retire as their chain ends.
    while (nx != NIL) {
        const float4* fp = fts4 + (size_t)nx * 4;
        float4 f0 = fp[0];
        float4 f1 = fp[1];
        float4 f2 = fp[2];
        float4 f3 = fp[3];
        unsigned nn = nxt[nx];
        s[0]  += f0.x; s[1]  += f0.y; s[2]  += f0.z; s[3]  += f0.w;
        s[4]  += f1.x; s[5]  += f1.y; s[6]  += f1.z; s[7]  += f1.w;
        s[8]  += f2.x; s[9]  += f2.y; s[10] += f2.z; s[11] += f2.w;
        s[12] += f3.x; s[13] += f3.y; s[14] += f3.z; s[15] += f3.w;
        cnt += 1.f;
        nx = nn;
    }

    if (cnt > 1.f) {              // cnt==1: s/1 is exact, skip IEEE div
        float c = cnt;
#pragma unroll
        for (int k = 0; k < 16; ++k) s[k] /= c;
    }

    float* obase = out + (size_t)b * C * V + v;
#pragma unroll
    for (int c = 0; c < 16; ++c)
        obase[(size_t)c * V] = s[c];   // 256B contiguous per wave per c
}

// ---- Fallback (tiny-workspace safety net): direct strided atomics into out.
__global__ __launch_bounds__(256) void zero_f4(float4* __restrict__ p, int n4) {
    int i = blockIdx.x * blockDim.x + threadIdx.x;
    if (i < n4) p[i] = make_float4(0.f, 0.f, 0.f, 0.f);
}

__global__ __launch_bounds__(256) void count_only(
    const float* __restrict__ pts, float* __restrict__ counts) {
    int idx = blockIdx.x * blockDim.x + threadIdx.x;
    if (idx >= B * N) return;
    int b = idx / N;
    const float* p = pts + (size_t)idx * 3;
    int v = voxel_of(p[0], p[1], p[2]);
    atomicAdd(counts + (size_t)b * V + v, 1.0f);
}

__global__ __launch_bounds__(256) void scatter_direct(
    const float* __restrict__ pts, const float* __restrict__ fts,
    const float* __restrict__ counts, float* __restrict__ out) {
    int idx = blockIdx.x * blockDim.x + threadIdx.x;
    if (idx >= B * N) return;
    int b = idx / N;
    const float* p = pts + (size_t)idx * 3;
    int v = voxel_of(p[0], p[1], p[2]);
    float cnt = counts[(size_t)b * V + v];
    const float* f = fts + (size_t)idx * C;
    float* o = out + (size_t)b * C * V + v;
#pragma unroll
    for (int c = 0; c < 16; ++c) atomicAdd(o + (size_t)c * V, f[c] / cnt);
}

}  // namespace

extern "C" void kernel_launch(void* const* d_in, const int* in_sizes, int n_in,
                              void* d_out, int out_size, void* d_ws, size_t ws_size,
                              hipStream_t stream) {
    const float* pts = (const float*)d_in[0];   // [B, N, 3]
    const float* fts = (const float*)d_in[1];   // [B, N, C]
    float* out = (float*)d_out;                 // [B, C, D, H, W]

    const int n_pts = B * N;                    // 400,000
    const int pt_blocks = (n_pts + 255) / 256;

    const size_t head_bytes = (size_t)BV * sizeof(unsigned);      // 16.8 MB
    const size_t nxt_bytes = (size_t)n_pts * sizeof(unsigned);    // 1.6 MB

    if (ws_size >= head_bytes + nxt_bytes) {
        unsigned* head = (unsigned*)d_ws;
        unsigned* nxt = head + (size_t)BV;

        int head_n4 = BV / 4;  // 1,048,576
        init_head<<<(head_n4 + 255) / 256, 256, 0, stream>>>((uint4*)head, head_n4);
        build_list<<<pt_blocks, 256, 0, stream>>>(pts, head, nxt);

        int fin_threads = BV;  // one thread per voxel
        finalize<<<(fin_threads + 255) / 256, 256, 0, stream>>>(
            head, nxt, (const float4*)fts, out);
    } else {
        // Safety net: direct atomic accumulation into out.
        float* counts = (float*)d_ws;
        int counts_f4 = BV / 4;
        zero_f4<<<(counts_f4 + 255) / 256, 256, 0, stream>>>((float4*)counts, counts_f4);
        int out_f4 = out_size / 4;
        zero_f4<<<(out_f4 + 255) / 256, 256, 0, stream>>>((float4*)out, out_f4);
        count_only<<<pt_blocks, 256, 0, stream>>>(pts, counts);
        scatter_direct<<<pt_blocks, 256, 0, stream>>>(pts, fts, counts, out);
    }
}